// Round 4
// baseline (2747.889 us; speedup 1.0000x reference)
//
#include <hip/hip_runtime.h>

// GPT-OSS MoE MLP on MI355X (gfx950).
// Round 3 (third resubmit; rounds 1-3 were infra failures: container crash,
// then 2x GPU acquisition timeout — kernel never ran): barrier-free GEMMs.
// The LDS-staged B tile forced a __syncthreads per K-step, and hipcc drains
// vmcnt(0) at every barrier -> each iteration exposed a full HBM round trip
// (MfmaUtil 10%, HBM 1.1 TB/s). Now each wave loads its own B fragments
// global->register (4x redundancy served by L1/L2; per-iter B working set
// 8KB fits L1), dequantizes in registers, and runs MFMA with no barriers at
// all. B+scales prefetched 2 K-steps deep, A 1 body deep, all statically
// indexed.

#define HD 2048
#define ID 2048
#define NE 16
#define NT 1024
#define NTOPK 4
#define NSLOTS (NT * NTOPK)   // 4096, exact

typedef unsigned short u16;
typedef __attribute__((ext_vector_type(8))) short short8;
typedef __attribute__((ext_vector_type(4))) float f32x4;

__device__ __forceinline__ float bf2f(u16 v) {
    return __uint_as_float(((unsigned)v) << 16);
}
__device__ __forceinline__ u16 f2bf(float f) {
    unsigned u = __float_as_uint(f);
    return (u16)((u + 0x7fffu + ((u >> 16) & 1u)) >> 16);
}

// ---------------- Kernel 1: router (exact f32) + x -> bf16 ----------------
__global__ void router_kernel(const float* __restrict__ x,
                              const float* __restrict__ rw,
                              const float* __restrict__ rb,
                              u16* __restrict__ xb,
                              int* __restrict__ counts,
                              int* __restrict__ topi,
                              float* __restrict__ topv) {
    const int t = blockIdx.x;
    const int lane = threadIdx.x;  // 64 threads = 1 wave

    float xr[32];
#pragma unroll
    for (int j = 0; j < 32; ++j) xr[j] = x[(size_t)t * HD + j * 64 + lane];
#pragma unroll
    for (int j = 0; j < 32; ++j) xb[(size_t)t * HD + j * 64 + lane] = f2bf(xr[j]);

    float lg[NE];
#pragma unroll
    for (int e = 0; e < NE; ++e) {
        const float* w = rw + (size_t)e * HD;
        float s = 0.f;
#pragma unroll
        for (int j = 0; j < 32; ++j) s = fmaf(xr[j], w[j * 64 + lane], s);
        for (int off = 32; off > 0; off >>= 1) s += __shfl_xor(s, off);
        lg[e] = s + rb[e];
    }

    if (lane == 0) {
        unsigned used = 0;
        float sv[NTOPK];
        int si[NTOPK];
#pragma unroll
        for (int k = 0; k < NTOPK; ++k) {
            float best = -1e30f;
            int bi = 0;
#pragma unroll
            for (int e = 0; e < NE; ++e) {
                if (!(used & (1u << e)) && lg[e] > best) { best = lg[e]; bi = e; }
            }
            used |= 1u << bi;
            sv[k] = best;
            si[k] = bi;
        }
        const float mx = sv[0];
        float p[NTOPK], sum = 0.f;
#pragma unroll
        for (int k = 0; k < NTOPK; ++k) { p[k] = __expf(sv[k] - mx); sum += p[k]; }
        const float inv = 1.0f / sum;
#pragma unroll
        for (int k = 0; k < NTOPK; ++k) {
            atomicAdd(&counts[si[k]], 1);
            topi[t * NTOPK + k] = si[k];
            topv[t * NTOPK + k] = p[k] * inv;
        }
    }
}

// ---------------- Kernel 2: exclusive prefix over counts ----------------
__global__ void bases_kernel(const int* __restrict__ counts, int* __restrict__ bases) {
    if (threadIdx.x == 0) {
        int acc = 0;
#pragma unroll
        for (int e = 0; e < NE; ++e) { bases[e] = acc; acc += counts[e]; }
    }
}

// ---------------- Kernel 3: slot assignment ----------------
__global__ void assign_kernel(const int* __restrict__ topi, const float* __restrict__ topv,
                              const int* __restrict__ bases, int* __restrict__ cursor,
                              int* __restrict__ tok_slot, float* __restrict__ wgt_slot) {
    const int t = blockIdx.x * 256 + threadIdx.x;
    if (t < NT) {
#pragma unroll
        for (int k = 0; k < NTOPK; ++k) {
            const int e = topi[t * NTOPK + k];
            const int s = atomicAdd(&cursor[e], 1);
            const int slot = bases[e] + s;
            tok_slot[slot] = t;
            wgt_slot[slot] = topv[t * NTOPK + k];
        }
    }
}

// ---- shared GEMM machinery (barrier-free, register dequant) --------------
// Per block: M=256 (4 waves x 64 rows), N=64, K full. Per wave per K-step
// (BK=32): 4 B n-frags (8 fp32/lane each) + 1 scale/frag, 4 A m-frags
// (short8/lane). B prefetch depth 2, A depth 1 body. No LDS, no barriers.

#define LOADB_(BB, SS, KB)                                               \
    _Pragma("unroll") for (int ni = 0; ni < 4; ++ni) {                   \
        const float4* p_ = (const float4*)(bp[ni] + (size_t)(KB) * 32);  \
        BB[ni][0] = p_[0];                                               \
        BB[ni][1] = p_[1];                                               \
        SS[ni] = sp[ni][(KB)];                                           \
    }
#define LOADA_(AA, KB)                                                   \
    _Pragma("unroll") for (int mi = 0; mi < 4; ++mi)                     \
        AA[mi] = *(const short8*)(ap[mi] + (size_t)(KB) * 32);
#define DEQ_(BB, SS, BF)                                                 \
    _Pragma("unroll") for (int ni = 0; ni < 4; ++ni) {                   \
        const float s_ = SS[ni];                                         \
        short8 f_;                                                       \
        f_[0] = (short)f2bf(BB[ni][0].x * s_);                           \
        f_[1] = (short)f2bf(BB[ni][0].y * s_);                           \
        f_[2] = (short)f2bf(BB[ni][0].z * s_);                           \
        f_[3] = (short)f2bf(BB[ni][0].w * s_);                           \
        f_[4] = (short)f2bf(BB[ni][1].x * s_);                           \
        f_[5] = (short)f2bf(BB[ni][1].y * s_);                           \
        f_[6] = (short)f2bf(BB[ni][1].z * s_);                           \
        f_[7] = (short)f2bf(BB[ni][1].w * s_);                           \
        BF[ni] = f_;                                                     \
    }
#define MFMA16_(AA, BF)                                                  \
    _Pragma("unroll") for (int mi = 0; mi < 4; ++mi)                     \
        _Pragma("unroll") for (int ni = 0; ni < 4; ++ni)                 \
            acc[mi][ni] = __builtin_amdgcn_mfma_f32_16x16x32_bf16(       \
                AA[mi], BF[ni], acc[mi][ni], 0, 0, 0);

// ---------------- Kernel 4: gate/up GEMM ----------------------------------
// grid: (ID/64, 4, NE*2); block 256 (4 waves stacked on M).
__global__ __launch_bounds__(256, 2) void gu_gemm(
    const u16* __restrict__ xb,
    const float* __restrict__ gate_blocks, const float* __restrict__ gate_scales,
    const float* __restrict__ gate_bias,
    const float* __restrict__ up_blocks, const float* __restrict__ up_scales,
    const float* __restrict__ up_bias,
    const int* __restrict__ counts, const int* __restrict__ bases,
    const int* __restrict__ tok_slot,
    u16* __restrict__ gbuf, u16* __restrict__ ubuf) {
    const int e = blockIdx.z >> 1, mat = blockIdx.z & 1;
    const int n_e = counts[e];
    const int mt = blockIdx.y;
    if (mt * 256 >= n_e) return;
    const int rows = min(256, n_e - mt * 256);
    const int base = bases[e] + mt * 256;
    const float* wb = mat ? up_blocks : gate_blocks;
    const float* wsc = mat ? up_scales : gate_scales;
    const float* wbias = mat ? up_bias : gate_bias;
    u16* outb = mat ? ubuf : gbuf;
    const int n0 = blockIdx.x * 64;

    const int tid = threadIdx.x;
    const int wave = tid >> 6, lane = tid & 63;
    const int lr = lane & 15, kch = lane >> 4;

    // A fragment base pointers (token gather, L2-resident xb)
    const u16* ap[4];
#pragma unroll
    for (int mi = 0; mi < 4; ++mi) {
        const int m = wave * 64 + mi * 16 + lr;
        const int tok = tok_slot[base + min(m, rows - 1)];
        ap[mi] = xb + (size_t)tok * HD + kch * 8;
    }

    // B fragment base pointers: col = n0 + ni*16 + lr, k offset kch*8
    const float* bp[4];
    const float* sp[4];
#pragma unroll
    for (int ni = 0; ni < 4; ++ni) {
        const int col = n0 + ni * 16 + lr;
        bp[ni] = wb + ((size_t)e * ID + col) * HD + kch * 8;
        sp[ni] = wsc + ((size_t)e * ID + col) * (HD / 32);
    }

    f32x4 acc[4][4];
#pragma unroll
    for (int a = 0; a < 4; ++a)
#pragma unroll
        for (int b = 0; b < 4; ++b) acc[a][b] = (f32x4){0.f, 0.f, 0.f, 0.f};

    float4 B0[4][2], B1[4][2];
    float S0[4], S1[4];
    short8 A0[4], A1[4];

    LOADB_(B0, S0, 0);
    LOADB_(B1, S1, 1);
    LOADA_(A0, 0);
    LOADA_(A1, 1);

    for (int kb = 0; kb < 64; kb += 2) {
        {
            short8 bf[4];
            DEQ_(B0, S0, bf);
            const int nk = (kb + 2 < 64) ? kb + 2 : 63;
            LOADB_(B0, S0, nk);       // issue next even-step B while MFMAs run
            MFMA16_(A0, bf);
            LOADA_(A0, nk);           // reload A for next even step (L2-hot)
        }
        {
            short8 bg[4];
            DEQ_(B1, S1, bg);
            const int nk = (kb + 3 < 64) ? kb + 3 : 63;
            LOADB_(B1, S1, nk);
            MFMA16_(A1, bg);
            LOADA_(A1, nk);
        }
    }

    // epilogue: C[m = (lane>>4)*4+reg][n = lane&15] (m89-verified layout)
    const int qq = lane >> 4;
#pragma unroll
    for (int ni = 0; ni < 4; ++ni) {
        const int colo = n0 + ni * 16 + lr;
        const float bv = wbias[e * ID + colo];
#pragma unroll
        for (int mi = 0; mi < 4; ++mi)
#pragma unroll
            for (int j = 0; j < 4; ++j) {
                const int ml = wave * 64 + mi * 16 + qq * 4 + j;
                if (ml < rows) outb[(size_t)(base + ml) * ID + colo] = f2bf(acc[mi][ni][j] + bv);
            }
    }
}

// ---------------- Kernel 5: GLU activation ----------------
__global__ void act_kernel(const u16* __restrict__ g, const u16* __restrict__ u,
                           u16* __restrict__ h) {
    const size_t i = (size_t)blockIdx.x * 256 + threadIdx.x;  // vec8 index
    const int4 gv = ((const int4*)g)[i];
    const int4 uv = ((const int4*)u)[i];
    const int gi[4] = {gv.x, gv.y, gv.z, gv.w};
    const int ui[4] = {uv.x, uv.y, uv.z, uv.w};
    int hi[4];
#pragma unroll
    for (int c = 0; c < 4; ++c) {
        float res[2];
#pragma unroll
        for (int p = 0; p < 2; ++p) {
            float gg = bf2f((u16)(((unsigned)gi[c] >> (16 * p)) & 0xffffu));
            float uu = bf2f((u16)(((unsigned)ui[c] >> (16 * p)) & 0xffffu));
            gg = fminf(gg, 7.0f);
            uu = fminf(fmaxf(uu, -7.0f), 7.0f);
            const float sig = 1.0f / (1.0f + __expf(-1.702f * gg));
            res[p] = (uu + 1.0f) * (gg * sig);
        }
        hi[c] = (int)((unsigned)f2bf(res[0]) | ((unsigned)f2bf(res[1]) << 16));
    }
    ((int4*)h)[i] = make_int4(hi[0], hi[1], hi[2], hi[3]);
}

// ---------------- Kernel 6: down GEMM + weighted scatter -------------------
__global__ __launch_bounds__(256, 2) void down_gemm(
    const u16* __restrict__ hbuf,
    const float* __restrict__ down_blocks, const float* __restrict__ down_scales,
    const float* __restrict__ down_bias,
    const int* __restrict__ counts, const int* __restrict__ bases,
    const int* __restrict__ tok_slot, const float* __restrict__ wgt_slot,
    float* __restrict__ out) {
    const int e = blockIdx.z;
    const int n_e = counts[e];
    const int mt = blockIdx.y;
    if (mt * 256 >= n_e) return;
    const int rows = min(256, n_e - mt * 256);
    const int base = bases[e] + mt * 256;
    const int n0 = blockIdx.x * 64;

    const int tid = threadIdx.x;
    const int wave = tid >> 6, lane = tid & 63;
    const int lr = lane & 15, kch = lane >> 4;

    const u16* ap[4];
#pragma unroll
    for (int mi = 0; mi < 4; ++mi) {
        const int m = wave * 64 + mi * 16 + lr;
        const int slot = base + min(m, rows - 1);
        ap[mi] = hbuf + (size_t)slot * ID + kch * 8;
    }

    const float* bp[4];
    const float* sp[4];
#pragma unroll
    for (int ni = 0; ni < 4; ++ni) {
        const int col = n0 + ni * 16 + lr;
        bp[ni] = down_blocks + ((size_t)e * HD + col) * ID + kch * 8;
        sp[ni] = down_scales + ((size_t)e * HD + col) * (ID / 32);
    }

    f32x4 acc[4][4];
#pragma unroll
    for (int a = 0; a < 4; ++a)
#pragma unroll
        for (int b = 0; b < 4; ++b) acc[a][b] = (f32x4){0.f, 0.f, 0.f, 0.f};

    float4 B0[4][2], B1[4][2];
    float S0[4], S1[4];
    short8 A0[4], A1[4];

    LOADB_(B0, S0, 0);
    LOADB_(B1, S1, 1);
    LOADA_(A0, 0);
    LOADA_(A1, 1);

    for (int kb = 0; kb < 64; kb += 2) {
        {
            short8 bf[4];
            DEQ_(B0, S0, bf);
            const int nk = (kb + 2 < 64) ? kb + 2 : 63;
            LOADB_(B0, S0, nk);
            MFMA16_(A0, bf);
            LOADA_(A0, nk);
        }
        {
            short8 bg[4];
            DEQ_(B1, S1, bg);
            const int nk = (kb + 3 < 64) ? kb + 3 : 63;
            LOADB_(B1, S1, nk);
            MFMA16_(A1, bg);
            LOADA_(A1, nk);
        }
    }

    const int qq = lane >> 4;
    float bvs[4];
#pragma unroll
    for (int ni = 0; ni < 4; ++ni) bvs[ni] = down_bias[e * HD + n0 + ni * 16 + lr];
#pragma unroll
    for (int mi = 0; mi < 4; ++mi)
#pragma unroll
        for (int j = 0; j < 4; ++j) {
            const int ml = wave * 64 + mi * 16 + qq * 4 + j;
            if (ml >= rows) continue;
            const int slot = base + ml;
            const int tok = tok_slot[slot];
            const float wg = wgt_slot[slot];
            float* orow = out + (size_t)tok * HD;
#pragma unroll
            for (int ni = 0; ni < 4; ++ni)
                atomicAdd(&orow[n0 + ni * 16 + lr], wg * (acc[mi][ni][j] + bvs[ni]));
        }
}

extern "C" void kernel_launch(void* const* d_in, const int* in_sizes, int n_in,
                              void* d_out, int out_size, void* d_ws, size_t ws_size,
                              hipStream_t stream) {
    const float* x           = (const float*)d_in[0];
    const float* rw          = (const float*)d_in[1];
    const float* rb          = (const float*)d_in[2];
    const float* gate_blocks = (const float*)d_in[3];
    const float* gate_scales = (const float*)d_in[4];
    const float* gate_bias   = (const float*)d_in[5];
    const float* up_blocks   = (const float*)d_in[6];
    const float* up_scales   = (const float*)d_in[7];
    const float* up_bias     = (const float*)d_in[8];
    const float* down_blocks = (const float*)d_in[9];
    const float* down_scales = (const float*)d_in[10];
    const float* down_bias   = (const float*)d_in[11];
    float* out = (float*)d_out;

    char* ws = (char*)d_ws;
    u16* xb     = (u16*)ws;                      //  4 MB
    u16* gbuf   = (u16*)(ws + (4 << 20));        // 16 MB
    u16* ubuf   = (u16*)(ws + (20 << 20));       // 16 MB
    u16* hbuf   = (u16*)(ws + (36 << 20));       // 16 MB
    int* counts = (int*)(ws + (52 << 20));       // 16
    int* cursor = counts + 16;                   // 16
    int* basesp = counts + 32;                   // 16
    int* topi   = counts + 64;                   // 4096
    float* topv = (float*)(counts + 64 + 4096);  // 4096
    int* tok_slot = (int*)(counts + 64 + 8192);  // 4096
    float* wgt_slot = (float*)(counts + 64 + 12288);

    hipMemsetAsync(d_out, 0, (size_t)NT * HD * sizeof(float), stream);
    hipMemsetAsync(counts, 0, 128, stream);  // counts + cursor

    router_kernel<<<NT, 64, 0, stream>>>(x, rw, rb, xb, counts, topi, topv);
    bases_kernel<<<1, 64, 0, stream>>>(counts, basesp);
    assign_kernel<<<NT / 256, 256, 0, stream>>>(topi, topv, basesp, cursor, tok_slot, wgt_slot);
    gu_gemm<<<dim3(ID / 64, 4, NE * 2), 256, 0, stream>>>(
        xb, gate_blocks, gate_scales, gate_bias, up_blocks, up_scales, up_bias,
        counts, basesp, tok_slot, gbuf, ubuf);
    act_kernel<<<(NSLOTS * ID / 8) / 256, 256, 0, stream>>>(gbuf, ubuf, hbuf);
    down_gemm<<<dim3(HD / 64, 4, NE), 256, 0, stream>>>(
        hbuf, down_blocks, down_scales, down_bias, counts, basesp, tok_slot, wgt_slot, out);
}